// Round 3
// baseline (534.610 us; speedup 1.0000x reference)
//
#include <hip/hip_runtime.h>
#include <cstdint>

typedef __bf16 bf16x8 __attribute__((ext_vector_type(8)));
typedef float f32x4 __attribute__((ext_vector_type(4)));
typedef unsigned short u16x8 __attribute__((ext_vector_type(8)));

#define NH 16
#define HD 128
#define SEQ 2048
#define DIM 2048
#define QKVO 6144   /* 48*128 */

__device__ __forceinline__ unsigned short f32_bf16(float f) {
  uint32_t u = __builtin_bit_cast(uint32_t, f);
  u += 0x7fffu + ((u >> 16) & 1u);
  return (unsigned short)(u >> 16);
}

// ---------------- elementwise f32 -> bf16 (8 elems/thread) -----------------
__global__ __launch_bounds__(256) void cvt_f32_bf16(
    const float* __restrict__ in, unsigned short* __restrict__ out) {
  long i = ((long)blockIdx.x * 256 + threadIdx.x) * 8;
  f32x4 a = *(const f32x4*)(in + i);
  f32x4 b = *(const f32x4*)(in + i + 4);
  u16x8 r;
#pragma unroll
  for (int j = 0; j < 4; j++) { r[j] = f32_bf16(a[j]); r[4 + j] = f32_bf16(b[j]); }
  *(u16x8*)(out + i) = r;
}

// ------- 64x64 tiled transpose + f32->bf16: out[C][R] = bf16(in[R][C])^T ---
__global__ __launch_bounds__(256) void transpose_f32_bf16(
    const float* __restrict__ in, unsigned short* __restrict__ out,
    int R, int C) {
  __shared__ unsigned short tile[64][65];
  const int t = threadIdx.x, tx = t & 63, ty = t >> 6;
  const long r0 = (long)blockIdx.y * 64, c0 = (long)blockIdx.x * 64;
  for (int i = 0; i < 16; i++) {
    int row = ty + i * 4;
    tile[row][tx] = f32_bf16(in[(r0 + row) * C + c0 + tx]);
  }
  __syncthreads();
  for (int i = 0; i < 16; i++) {
    int row = ty + i * 4;
    out[(c0 + row) * R + r0 + tx] = tile[tx][row];
  }
}

// ------------- extract V head-slices from qkv, transpose to VT[bh][d][t] ---
__global__ __launch_bounds__(256) void transpose_v(
    const unsigned short* __restrict__ qkv, unsigned short* __restrict__ vT) {
  // grid: x = SEQ/64, y = HD/64 (=2), z = B*NH
  __shared__ unsigned short tile[64][65];
  const int t = threadIdx.x, tx = t & 63, ty = t >> 6;
  const int bh = blockIdx.z, b = bh >> 4, h = bh & 15;
  const long t0 = (long)blockIdx.x * 64;
  const int d0 = blockIdx.y * 64;
  const unsigned short* src = qkv + (long)b * SEQ * QKVO + 2 * NH * HD + h * HD;
  for (int i = 0; i < 16; i++) {
    int row = ty + i * 4;
    tile[row][tx] = src[(t0 + row) * QKVO + d0 + tx];
  }
  __syncthreads();
  unsigned short* dst = vT + ((long)bh * HD + d0) * SEQ + t0;
  for (int i = 0; i < 16; i++) {
    int row = ty + i * 4;
    dst[(long)row * SEQ + tx] = tile[tx][row];
  }
}

// ---- C[:,ldc] = A[:,lda] @ BT[:,ldb]^T  (bf16 in, fp32 accum, OutT out) ---
template <typename OutT>
__global__ __launch_bounds__(256) void gemm_bt(
    const unsigned short* __restrict__ A, int lda,
    const unsigned short* __restrict__ BT, int ldb,
    OutT* __restrict__ C, int ldc, int K) {
  __shared__ __align__(16) unsigned short As[128 * 32];
  __shared__ __align__(16) unsigned short Bs[128 * 32];
  const int t = threadIdx.x;
  const int lane = t & 63, w = t >> 6;
  const int quad = lane >> 4, l16 = lane & 15;
  const int wm = (w & 1) * 64, wn = (w >> 1) * 64;
  const long m0 = (long)blockIdx.y * 128, n0 = (long)blockIdx.x * 128;

  f32x4 acc[4][4] = {};
  const int rowA = t >> 2, kslot = (t & 3) * 8;
  const unsigned short* Ag = A + (m0 + rowA) * (long)lda + kslot;
  const unsigned short* Bg = BT + (n0 + rowA) * (long)ldb + kslot;

  for (int k0 = 0; k0 < K; k0 += 32) {
    // global loads issued before the barrier: overlap prev iteration's MFMAs
    bf16x8 a0 = *(const bf16x8*)(Ag + k0);
    bf16x8 a1 = *(const bf16x8*)(Ag + 64 * (long)lda + k0);
    bf16x8 b0 = *(const bf16x8*)(Bg + k0);
    bf16x8 b1 = *(const bf16x8*)(Bg + 64 * (long)ldb + k0);
    __syncthreads();  // prev iteration's LDS readers done
    *(bf16x8*)&As[rowA * 32 + kslot] = a0;
    *(bf16x8*)&As[(64 + rowA) * 32 + kslot] = a1;
    *(bf16x8*)&Bs[rowA * 32 + kslot] = b0;
    *(bf16x8*)&Bs[(64 + rowA) * 32 + kslot] = b1;
    __syncthreads();  // staged tile visible

    bf16x8 af[4], bf[4];
#pragma unroll
    for (int mt = 0; mt < 4; mt++)
      af[mt] = *(const bf16x8*)&As[(wm + mt * 16 + l16) * 32 + quad * 8];
#pragma unroll
    for (int nt = 0; nt < 4; nt++)
      bf[nt] = *(const bf16x8*)&Bs[(wn + nt * 16 + l16) * 32 + quad * 8];
#pragma unroll
    for (int mt = 0; mt < 4; mt++)
#pragma unroll
      for (int nt = 0; nt < 4; nt++)
        acc[mt][nt] = __builtin_amdgcn_mfma_f32_16x16x32_bf16(
            af[mt], bf[nt], acc[mt][nt], 0, 0, 0);
  }

  // epilogue: C/D layout col=l16, row=quad*4+r
#pragma unroll
  for (int mt = 0; mt < 4; mt++) {
    long row = m0 + wm + mt * 16 + quad * 4;
#pragma unroll
    for (int r = 0; r < 4; r++) {
      OutT* crow = C + (row + r) * (long)ldc + n0 + wn + l16;
#pragma unroll
      for (int nt = 0; nt < 4; nt++) {
        float v = acc[mt][nt][r];
        if constexpr (sizeof(OutT) == 2) crow[nt * 16] = f32_bf16(v);
        else                             crow[nt * 16] = v;
      }
    }
  }
}

// ---------------- flash attention: 64 q-rows/block, 64-key chunks ----------
// Writes O in place over the Q columns of qkv (each block exclusively owns
// its 64-row x 128-col Q slice: reads it at block start, writes O at end).
#define KSTR 136  /* 64 x 136 padded K tile  */
#define VSTR 72   /* 128 x 72 padded VT tile */
__global__ __launch_bounds__(256) void attn_kernel(
    unsigned short* qkv, const unsigned short* __restrict__ vT) {
  __shared__ __align__(16) unsigned short Ks[64 * KSTR];
  __shared__ __align__(16) unsigned short Vs[128 * VSTR];
  __shared__ __align__(16) unsigned short Ps[4][16 * VSTR];

  const int t = threadIdx.x, lane = t & 63, w = t >> 6;
  const int quad = lane >> 4, l16 = lane & 15;
  const int q0 = blockIdx.x * 64, h = blockIdx.y, b = blockIdx.z;
  const long row0 = (long)b * SEQ;

  // Q fragments: A-layout, q-row = w*16 + l16, k(d) = c*32 + quad*8 + j
  bf16x8 qf[4];
  {
    const unsigned short* Qp =
        qkv + (row0 + q0 + w * 16 + l16) * (long)QKVO + h * HD + quad * 8;
#pragma unroll
    for (int c = 0; c < 4; c++) qf[c] = *(const bf16x8*)(Qp + c * 32);
  }

  float m_i[4], l_i[4];
  f32x4 o[8] = {};
#pragma unroll
  for (int r = 0; r < 4; r++) { m_i[r] = -1e30f; l_i[r] = 0.f; }
  const float sm_scale = 0.08838834764831845f * 1.4426950408889634f; // 1/sqrt(128)*log2(e)

  const unsigned short* Kg = qkv + row0 * QKVO + NH * HD + h * HD;
  const unsigned short* Vg = vT + ((long)(b * NH + h)) * HD * SEQ;

  for (int kc = 0; kc < SEQ; kc += 64) {
    bf16x8 kr[4], vr[4];
#pragma unroll
    for (int i = 0; i < 4; i++) {
      int s = i * 256 + t;  // K tile: [key = s>>4][dchunk = s&15]
      kr[i] = *(const bf16x8*)(Kg + (long)(kc + (s >> 4)) * QKVO + (s & 15) * 8);
    }
#pragma unroll
    for (int i = 0; i < 4; i++) {
      int s = i * 256 + t;  // VT tile: [d = s>>3][keychunk = s&7]
      vr[i] = *(const bf16x8*)(Vg + (long)(s >> 3) * SEQ + kc + (s & 7) * 8);
    }
    __syncthreads();  // prev chunk's LDS readers done
#pragma unroll
    for (int i = 0; i < 4; i++) {
      int s = i * 256 + t;
      *(bf16x8*)&Ks[(s >> 4) * KSTR + (s & 15) * 8] = kr[i];
    }
#pragma unroll
    for (int i = 0; i < 4; i++) {
      int s = i * 256 + t;
      *(bf16x8*)&Vs[(s >> 3) * VSTR + (s & 7) * 8] = vr[i];
    }
    __syncthreads();  // tiles visible

    // S = Q K^T : C-layout rows = q (quad*4+r), cols = key (kt*16+l16)
    f32x4 s4[4];
#pragma unroll
    for (int kt = 0; kt < 4; kt++) {
      f32x4 a = {};
#pragma unroll
      for (int c = 0; c < 4; c++) {
        bf16x8 kf = *(const bf16x8*)&Ks[(kt * 16 + l16) * KSTR + c * 32 + quad * 8];
        a = __builtin_amdgcn_mfma_f32_16x16x32_bf16(qf[c], kf, a, 0, 0, 0);
      }
      s4[kt] = a;
    }
#pragma unroll
    for (int kt = 0; kt < 4; kt++)
#pragma unroll
      for (int r = 0; r < 4; r++) s4[kt][r] *= sm_scale;

    // online softmax (base-2): stats reduced over the 16 lanes of each quad
#pragma unroll
    for (int r = 0; r < 4; r++) {
      float mx = fmaxf(fmaxf(s4[0][r], s4[1][r]), fmaxf(s4[2][r], s4[3][r]));
#pragma unroll
      for (int d = 1; d < 16; d <<= 1) mx = fmaxf(mx, __shfl_xor(mx, d, 64));
      float mn = fmaxf(m_i[r], mx);
      float alpha = exp2f(m_i[r] - mn);
      m_i[r] = mn;
      float ls = 0.f;
#pragma unroll
      for (int kt = 0; kt < 4; kt++) {
        float pv = exp2f(s4[kt][r] - mn);
        s4[kt][r] = pv;
        ls += pv;
      }
#pragma unroll
      for (int d = 1; d < 16; d <<= 1) ls += __shfl_xor(ls, d, 64);
      l_i[r] = l_i[r] * alpha + ls;
#pragma unroll
      for (int dt = 0; dt < 8; dt++) o[dt][r] *= alpha;
    }

    // P: C-layout -> LDS -> A-layout (per-wave buffer)
#pragma unroll
    for (int kt = 0; kt < 4; kt++)
#pragma unroll
      for (int r = 0; r < 4; r++)
        Ps[w][(quad * 4 + r) * VSTR + kt * 16 + l16] = f32_bf16(s4[kt][r]);
    __syncthreads();  // memory fence for the type-punned read below

    // O += P V : A = P[q][key], B = V[key][d] (VT rows contiguous in key)
#pragma unroll
    for (int cc = 0; cc < 2; cc++) {
      bf16x8 pf = *(const bf16x8*)&Ps[w][l16 * VSTR + cc * 32 + quad * 8];
#pragma unroll
      for (int dt = 0; dt < 8; dt++) {
        bf16x8 vf = *(const bf16x8*)&Vs[(dt * 16 + l16) * VSTR + cc * 32 + quad * 8];
        o[dt] = __builtin_amdgcn_mfma_f32_16x16x32_bf16(pf, vf, o[dt], 0, 0, 0);
      }
    }
  }

  // epilogue: write O over the Q columns of qkv
  long orow = row0 + q0 + w * 16 + quad * 4;
  unsigned short* Op = qkv + orow * (long)QKVO + h * HD + l16;
#pragma unroll
  for (int r = 0; r < 4; r++) {
    float inv = 1.f / l_i[r];
#pragma unroll
    for (int dt = 0; dt < 8; dt++)
      Op[(long)r * QKVO + dt * 16] = f32_bf16(o[dt][r] * inv);
  }
}

extern "C" void kernel_launch(void* const* d_in, const int* in_sizes, int n_in,
                              void* d_out, int out_size, void* d_ws, size_t ws_size,
                              hipStream_t stream) {
  const float* x     = (const float*)d_in[0];  // [4096][2048] f32
  const float* w_qkv = (const float*)d_in[1];  // [2048][6144] f32
  const float* w_out = (const float*)d_in[2];  // [2048][2048] f32
  float* out = (float*)d_out;                  // [4096][2048] f32

  // Workspace plan (peak 92,274,688 B):
  //   [0,        50331648)  qkv  bf16 [4096][6144] (Q cols later = O)
  //   [50331648, 67108864)  xbf  bf16 [4096][2048]
  //   [67108864, 92274688)  wqkvT bf16 [6144][2048]  (dead after GEMM1)
  //   [67108864, 83886080)    vT bf16 [32][128][2048] (overlays wqkvT)
  //   [83886080, 92274688)    woutT bf16 [2048][2048] (overlays wqkvT tail)
  char* ws = (char*)d_ws;
  unsigned short* qkv   = (unsigned short*)ws;
  unsigned short* xbf   = (unsigned short*)(ws + 50331648);
  unsigned short* wqkvT = (unsigned short*)(ws + 67108864);
  unsigned short* vTbuf = (unsigned short*)(ws + 67108864);
  unsigned short* woutT = (unsigned short*)(ws + 83886080);

  dim3 blk(256);
  // 1) convert x to bf16; transpose+convert w_qkv
  cvt_f32_bf16<<<4096, blk, 0, stream>>>(x, xbf);  // 8388608 / (256*8)
  transpose_f32_bf16<<<dim3(QKVO / 64, DIM / 64), blk, 0, stream>>>(w_qkv, wqkvT, DIM, QKVO);
  // 2) QKV projection: qkv = xbf @ w_qkv  (bf16 out)
  gemm_bt<unsigned short><<<dim3(QKVO / 128, 4096 / 128), blk, 0, stream>>>(
      xbf, DIM, wqkvT, DIM, qkv, QKVO, DIM);
  // 3) V transpose per (b,h) into vT (overlays dead wqkvT)
  transpose_v<<<dim3(SEQ / 64, HD / 64, 2 * NH), blk, 0, stream>>>(qkv, vTbuf);
  // 4) transpose+convert w_out (overlays wqkvT tail; after GEMM1)
  transpose_f32_bf16<<<dim3(DIM / 64, DIM / 64), blk, 0, stream>>>(w_out, woutT, DIM, DIM);
  // 5) flash attention; O written over Q columns of qkv
  attn_kernel<<<dim3(SEQ / 64, NH, 2), blk, 0, stream>>>(qkv, vTbuf);
  // 6) output projection: out(f32) = O @ w_out  (A = qkv cols [0,2048), lda=6144)
  gemm_bt<float><<<dim3(DIM / 128, 4096 / 128), blk, 0, stream>>>(
      qkv, QKVO, woutT, DIM, out, DIM, DIM);
}

// Round 4
// 490.936 us; speedup vs baseline: 1.0890x; 1.0890x over previous
//
#include <hip/hip_runtime.h>
#include <cstdint>

typedef __bf16 bf16x8 __attribute__((ext_vector_type(8)));
typedef float f32x4 __attribute__((ext_vector_type(4)));
typedef unsigned short u16x8 __attribute__((ext_vector_type(8)));

#define NH 16
#define HD 128
#define SEQ 2048
#define DIM 2048
#define QKVO 6144   /* 48*128 */

__device__ __forceinline__ unsigned short f32_bf16(float f) {
  uint32_t u = __builtin_bit_cast(uint32_t, f);
  u += 0x7fffu + ((u >> 16) & 1u);
  return (unsigned short)(u >> 16);
}

// async global->LDS, 16B/lane. lds dst must be wave-uniform base (+lane*16B).
__device__ __forceinline__ void gl2lds16(const void* g, void* l) {
  __builtin_amdgcn_global_load_lds(
      (const __attribute__((address_space(1))) uint32_t*)g,
      (__attribute__((address_space(3))) uint32_t*)l,
      16, 0, 0);
}

// ---------------- elementwise f32 -> bf16 (8 elems/thread) -----------------
__global__ __launch_bounds__(256) void cvt_f32_bf16(
    const float* __restrict__ in, unsigned short* __restrict__ out) {
  long i = ((long)blockIdx.x * 256 + threadIdx.x) * 8;
  f32x4 a = *(const f32x4*)(in + i);
  f32x4 b = *(const f32x4*)(in + i + 4);
  u16x8 r;
#pragma unroll
  for (int j = 0; j < 4; j++) { r[j] = f32_bf16(a[j]); r[4 + j] = f32_bf16(b[j]); }
  *(u16x8*)(out + i) = r;
}

// ------- 64x64 tiled transpose + f32->bf16: out[C][R] = bf16(in[R][C])^T ---
__global__ __launch_bounds__(256) void transpose_f32_bf16(
    const float* __restrict__ in, unsigned short* __restrict__ out,
    int R, int C) {
  __shared__ unsigned short tile[64][65];
  const int t = threadIdx.x, tx = t & 63, ty = t >> 6;
  const long r0 = (long)blockIdx.y * 64, c0 = (long)blockIdx.x * 64;
  for (int i = 0; i < 16; i++) {
    int row = ty + i * 4;
    tile[row][tx] = f32_bf16(in[(r0 + row) * C + c0 + tx]);
  }
  __syncthreads();
  for (int i = 0; i < 16; i++) {
    int row = ty + i * 4;
    out[(c0 + row) * R + r0 + tx] = tile[tx][row];
  }
}

// ------------- extract V head-slices from qkv, transpose to VT[bh][d][t] ---
__global__ __launch_bounds__(256) void transpose_v(
    const unsigned short* __restrict__ qkv, unsigned short* __restrict__ vT) {
  // grid: x = SEQ/64, y = HD/64 (=2), z = B*NH
  __shared__ unsigned short tile[64][65];
  const int t = threadIdx.x, tx = t & 63, ty = t >> 6;
  const int bh = blockIdx.z, b = bh >> 4, h = bh & 15;
  const long t0 = (long)blockIdx.x * 64;
  const int d0 = blockIdx.y * 64;
  const unsigned short* src = qkv + (long)b * SEQ * QKVO + 2 * NH * HD + h * HD;
  for (int i = 0; i < 16; i++) {
    int row = ty + i * 4;
    tile[row][tx] = src[(t0 + row) * QKVO + d0 + tx];
  }
  __syncthreads();
  unsigned short* dst = vT + ((long)bh * HD + d0) * SEQ + t0;
  for (int i = 0; i < 16; i++) {
    int row = ty + i * 4;
    dst[(long)row * SEQ + tx] = tile[tx][row];
  }
}

// ---- C[:,ldc] = A[:,lda] @ BT[:,ldb]^T  (bf16 in, fp32 accum, OutT out) ---
// m97 structure: global_load_lds width=16 staging, 128x128 tile, 4x4 acc/wave
template <typename OutT>
__global__ __launch_bounds__(256) void gemm_bt(
    const unsigned short* __restrict__ A, int lda,
    const unsigned short* __restrict__ BT, int ldb,
    OutT* __restrict__ C, int ldc, int K) {
  __shared__ __align__(16) unsigned short As[128 * 32];
  __shared__ __align__(16) unsigned short Bs[128 * 32];
  const int t = threadIdx.x;
  const int lane = t & 63, w = t >> 6;
  const int quad = lane >> 4, l16 = lane & 15;
  const int wm = (w & 1) * 64, wn = (w >> 1) * 64;
  const long m0 = (long)blockIdx.y * 128, n0 = (long)blockIdx.x * 128;

  f32x4 acc[4][4] = {};
  const int rowA = t >> 2, kslot = (t & 3) * 8;
  const unsigned short* Ag = A + (m0 + rowA) * (long)lda + kslot;
  const unsigned short* Bg = BT + (n0 + rowA) * (long)ldb + kslot;
  // lane L of wave w stages to As[w*512 + L*8] == As[rowA*32+kslot] (verified map)
  unsigned short* AsBase = &As[w * 512];
  unsigned short* BsBase = &Bs[w * 512];

  for (int k0 = 0; k0 < K; k0 += 32) {
    __syncthreads();  // prev iteration's LDS readers done
    gl2lds16(Ag + k0, AsBase);
    gl2lds16(Ag + 64 * (long)lda + k0, AsBase + 2048);
    gl2lds16(Bg + k0, BsBase);
    gl2lds16(Bg + 64 * (long)ldb + k0, BsBase + 2048);
    __syncthreads();  // drains vmcnt: staged tile visible

    bf16x8 af[4], bf[4];
#pragma unroll
    for (int mt = 0; mt < 4; mt++)
      af[mt] = *(const bf16x8*)&As[(wm + mt * 16 + l16) * 32 + quad * 8];
#pragma unroll
    for (int nt = 0; nt < 4; nt++)
      bf[nt] = *(const bf16x8*)&Bs[(wn + nt * 16 + l16) * 32 + quad * 8];
#pragma unroll
    for (int mt = 0; mt < 4; mt++)
#pragma unroll
      for (int nt = 0; nt < 4; nt++)
        acc[mt][nt] = __builtin_amdgcn_mfma_f32_16x16x32_bf16(
            af[mt], bf[nt], acc[mt][nt], 0, 0, 0);
  }

  // epilogue: C/D layout col=l16, row=quad*4+r
#pragma unroll
  for (int mt = 0; mt < 4; mt++) {
    long row = m0 + wm + mt * 16 + quad * 4;
#pragma unroll
    for (int r = 0; r < 4; r++) {
      OutT* crow = C + (row + r) * (long)ldc + n0 + wn + l16;
#pragma unroll
      for (int nt = 0; nt < 4; nt++) {
        float v = acc[mt][nt][r];
        if constexpr (sizeof(OutT) == 2) crow[nt * 16] = f32_bf16(v);
        else                             crow[nt * 16] = v;
      }
    }
  }
}

// -------- flash attention: 128 q/block, 32 q/wave (mt=2), 64-key chunks ----
// Software-pipelined K/V prefetch into regs; P roundtrip per-wave (no barrier).
// Writes O in place over the Q columns of qkv.
#define KSTR 136  /* 64 x 136 padded K tile  */
#define VSTR 72   /* 128 x 72 padded VT tile */
__global__ __launch_bounds__(256, 2) void attn_kernel(
    unsigned short* qkv, const unsigned short* __restrict__ vT) {
  __shared__ __align__(16) unsigned short Ks[64 * KSTR];
  __shared__ __align__(16) unsigned short Vs[128 * VSTR];
  __shared__ __align__(16) unsigned short Ps[4][32 * VSTR];

  const int t = threadIdx.x, lane = t & 63, w = t >> 6;
  const int quad = lane >> 4, l16 = lane & 15;
  const int q0 = blockIdx.x * 128, h = blockIdx.y, b = blockIdx.z;
  const long row0 = (long)b * SEQ;

  // Q fragments (2 m-tiles): A-layout row = w*32 + mt*16 + l16
  bf16x8 qf[2][4];
#pragma unroll
  for (int mt = 0; mt < 2; mt++) {
    const unsigned short* Qp =
        qkv + (row0 + q0 + w * 32 + mt * 16 + l16) * (long)QKVO + h * HD + quad * 8;
#pragma unroll
    for (int c = 0; c < 4; c++) qf[mt][c] = *(const bf16x8*)(Qp + c * 32);
  }

  float m_i[2][4], l_i[2][4];
  f32x4 o[2][8] = {};
#pragma unroll
  for (int mt = 0; mt < 2; mt++)
#pragma unroll
    for (int r = 0; r < 4; r++) { m_i[mt][r] = -1e30f; l_i[mt][r] = 0.f; }
  const float sm_scale = 0.08838834764831845f * 1.4426950408889634f; // 1/sqrt(128)*log2(e)

  const unsigned short* Kg = qkv + row0 * QKVO + NH * HD + h * HD;
  const unsigned short* Vg = vT + ((long)(b * NH + h)) * HD * SEQ;

  // prefetch chunk 0 into regs
  bf16x8 kr[4], vr[4];
#pragma unroll
  for (int i = 0; i < 4; i++) {
    int s = i * 256 + t;  // K tile: [key = s>>4][dchunk = s&15]
    kr[i] = *(const bf16x8*)(Kg + (long)(s >> 4) * QKVO + (s & 15) * 8);
  }
#pragma unroll
  for (int i = 0; i < 4; i++) {
    int s = i * 256 + t;  // VT tile: [d = s>>3][keychunk = s&7]
    vr[i] = *(const bf16x8*)(Vg + (long)(s >> 3) * SEQ + (s & 7) * 8);
  }

  for (int kc = 0; kc < SEQ; kc += 64) {
    __syncthreads();  // prev chunk's LDS readers done
#pragma unroll
    for (int i = 0; i < 4; i++) {
      int s = i * 256 + t;
      *(bf16x8*)&Ks[(s >> 4) * KSTR + (s & 15) * 8] = kr[i];
    }
#pragma unroll
    for (int i = 0; i < 4; i++) {
      int s = i * 256 + t;
      *(bf16x8*)&Vs[(s >> 3) * VSTR + (s & 7) * 8] = vr[i];
    }
    __syncthreads();  // tiles visible

    // issue next chunk's global loads now; latency hidden under compute
    if (kc + 64 < SEQ) {
#pragma unroll
      for (int i = 0; i < 4; i++) {
        int s = i * 256 + t;
        kr[i] = *(const bf16x8*)(Kg + (long)(kc + 64 + (s >> 4)) * QKVO + (s & 15) * 8);
      }
#pragma unroll
      for (int i = 0; i < 4; i++) {
        int s = i * 256 + t;
        vr[i] = *(const bf16x8*)(Vg + (long)(s >> 3) * SEQ + kc + 64 + (s & 7) * 8);
      }
    }

    // S = Q K^T : per kt, K-frag shared across both m-tiles
    f32x4 s4[2][4];
#pragma unroll
    for (int kt = 0; kt < 4; kt++) {
      f32x4 a0 = {}, a1 = {};
#pragma unroll
      for (int c = 0; c < 4; c++) {
        bf16x8 kf = *(const bf16x8*)&Ks[(kt * 16 + l16) * KSTR + c * 32 + quad * 8];
        a0 = __builtin_amdgcn_mfma_f32_16x16x32_bf16(qf[0][c], kf, a0, 0, 0, 0);
        a1 = __builtin_amdgcn_mfma_f32_16x16x32_bf16(qf[1][c], kf, a1, 0, 0, 0);
      }
      s4[0][kt] = a0; s4[1][kt] = a1;
    }

    // online softmax (base-2), 8 independent row-chains (2 mt x 4 r)
#pragma unroll
    for (int mt = 0; mt < 2; mt++)
#pragma unroll
      for (int r = 0; r < 4; r++) {
        float v0 = s4[mt][0][r] * sm_scale, v1 = s4[mt][1][r] * sm_scale;
        float v2 = s4[mt][2][r] * sm_scale, v3 = s4[mt][3][r] * sm_scale;
        float mx = fmaxf(fmaxf(v0, v1), fmaxf(v2, v3));
#pragma unroll
        for (int d = 1; d < 16; d <<= 1) mx = fmaxf(mx, __shfl_xor(mx, d, 64));
        float mn = fmaxf(m_i[mt][r], mx);
        float alpha = exp2f(m_i[mt][r] - mn);
        m_i[mt][r] = mn;
        float p0 = exp2f(v0 - mn), p1 = exp2f(v1 - mn);
        float p2 = exp2f(v2 - mn), p3 = exp2f(v3 - mn);
        s4[mt][0][r] = p0; s4[mt][1][r] = p1; s4[mt][2][r] = p2; s4[mt][3][r] = p3;
        float ls = (p0 + p1) + (p2 + p3);
#pragma unroll
        for (int d = 1; d < 16; d <<= 1) ls += __shfl_xor(ls, d, 64);
        l_i[mt][r] = l_i[mt][r] * alpha + ls;
#pragma unroll
        for (int dt = 0; dt < 8; dt++) o[mt][dt][r] *= alpha;
      }

    // P: C-layout -> per-wave LDS -> A-layout (no block barrier needed)
#pragma unroll
    for (int mt = 0; mt < 2; mt++)
#pragma unroll
      for (int kt = 0; kt < 4; kt++)
#pragma unroll
        for (int r = 0; r < 4; r++)
          Ps[w][(mt * 16 + quad * 4 + r) * VSTR + kt * 16 + l16] = f32_bf16(s4[mt][kt][r]);
    asm volatile("s_waitcnt lgkmcnt(0)" ::: "memory");

    // O += P V : V-frag shared across both m-tiles
#pragma unroll
    for (int cc = 0; cc < 2; cc++) {
      bf16x8 pf0 = *(const bf16x8*)&Ps[w][(l16) * VSTR + cc * 32 + quad * 8];
      bf16x8 pf1 = *(const bf16x8*)&Ps[w][(16 + l16) * VSTR + cc * 32 + quad * 8];
#pragma unroll
      for (int dt = 0; dt < 8; dt++) {
        bf16x8 vf = *(const bf16x8*)&Vs[(dt * 16 + l16) * VSTR + cc * 32 + quad * 8];
        o[0][dt] = __builtin_amdgcn_mfma_f32_16x16x32_bf16(pf0, vf, o[0][dt], 0, 0, 0);
        o[1][dt] = __builtin_amdgcn_mfma_f32_16x16x32_bf16(pf1, vf, o[1][dt], 0, 0, 0);
      }
    }
  }

  // epilogue: write O over the Q columns of qkv
#pragma unroll
  for (int mt = 0; mt < 2; mt++) {
    long orow = row0 + q0 + w * 32 + mt * 16 + quad * 4;
    unsigned short* Op = qkv + orow * (long)QKVO + h * HD + l16;
#pragma unroll
    for (int r = 0; r < 4; r++) {
      float inv = 1.f / l_i[mt][r];
#pragma unroll
      for (int dt = 0; dt < 8; dt++)
        Op[(long)r * QKVO + dt * 16] = f32_bf16(o[mt][dt][r] * inv);
    }
  }
}

extern "C" void kernel_launch(void* const* d_in, const int* in_sizes, int n_in,
                              void* d_out, int out_size, void* d_ws, size_t ws_size,
                              hipStream_t stream) {
  const float* x     = (const float*)d_in[0];  // [4096][2048] f32
  const float* w_qkv = (const float*)d_in[1];  // [2048][6144] f32
  const float* w_out = (const float*)d_in[2];  // [2048][2048] f32
  float* out = (float*)d_out;                  // [4096][2048] f32

  // Workspace plan (peak 92,274,688 B):
  //   [0,        50331648)  qkv  bf16 [4096][6144] (Q cols later = O)
  //   [50331648, 67108864)  xbf  bf16 [4096][2048]
  //   [67108864, 92274688)  wqkvT bf16 [6144][2048]  (dead after GEMM1)
  //   [67108864, 83886080)    vT bf16 [32][128][2048] (overlays wqkvT)
  //   [83886080, 92274688)    woutT bf16 [2048][2048] (overlays wqkvT tail)
  char* ws = (char*)d_ws;
  unsigned short* qkv   = (unsigned short*)ws;
  unsigned short* xbf   = (unsigned short*)(ws + 50331648);
  unsigned short* wqkvT = (unsigned short*)(ws + 67108864);
  unsigned short* vTbuf = (unsigned short*)(ws + 67108864);
  unsigned short* woutT = (unsigned short*)(ws + 83886080);

  dim3 blk(256);
  // 1) convert x to bf16; transpose+convert w_qkv
  cvt_f32_bf16<<<4096, blk, 0, stream>>>(x, xbf);
  transpose_f32_bf16<<<dim3(QKVO / 64, DIM / 64), blk, 0, stream>>>(w_qkv, wqkvT, DIM, QKVO);
  // 2) QKV projection: qkv = xbf @ w_qkv  (bf16 out)
  gemm_bt<unsigned short><<<dim3(QKVO / 128, 4096 / 128), blk, 0, stream>>>(
      xbf, DIM, wqkvT, DIM, qkv, QKVO, DIM);
  // 3) V transpose per (b,h) into vT (overlays dead wqkvT)
  transpose_v<<<dim3(SEQ / 64, HD / 64, 2 * NH), blk, 0, stream>>>(qkv, vTbuf);
  // 4) transpose+convert w_out (overlays wqkvT tail; after GEMM1)
  transpose_f32_bf16<<<dim3(DIM / 64, DIM / 64), blk, 0, stream>>>(w_out, woutT, DIM, DIM);
  // 5) flash attention; O written over Q columns of qkv (128 q-rows/block)
  attn_kernel<<<dim3(SEQ / 128, NH, 2), blk, 0, stream>>>(qkv, vTbuf);
  // 6) output projection: out(f32) = O @ w_out  (A = qkv cols [0,2048), lda=6144)
  gemm_bt<float><<<dim3(DIM / 128, 4096 / 128), blk, 0, stream>>>(
      qkv, QKVO, woutT, DIM, out, DIM, DIM);
}